// Round 1
// 889.952 us; speedup vs baseline: 1.0377x; 1.0377x over previous
//
#include <hip/hip_runtime.h>

#define N_ 4
#define P_ 2048
#define D_ 512
#define H_ 8
#define HD_ 64

typedef __attribute__((ext_vector_type(8))) short short8;
typedef __attribute__((ext_vector_type(4))) float f32x4;

__device__ __forceinline__ f32x4 mfma16(short8 a, short8 b, f32x4 c){
  return __builtin_amdgcn_mfma_f32_16x16x32_bf16(a, b, c, 0, 0, 0);
}

__device__ __forceinline__ unsigned short f2bf(float f){
  union { float fv; unsigned u; } v; v.fv = f;
  unsigned r = v.u + 0x7fffu + ((v.u >> 16) & 1u);
  return (unsigned short)(r >> 16);
}
__device__ __forceinline__ float bf2f(unsigned short b){
  union { unsigned u; float fv; } v; v.u = ((unsigned)b) << 16;
  return v.fv;
}
__device__ __forceinline__ short8 load8f_bf(const float* p){
  f32x4 a = *(const f32x4*)p;
  f32x4 b = *(const f32x4*)(p + 4);
  short8 v;
  v[0]=(short)f2bf(a[0]); v[1]=(short)f2bf(a[1]); v[2]=(short)f2bf(a[2]); v[3]=(short)f2bf(a[3]);
  v[4]=(short)f2bf(b[0]); v[5]=(short)f2bf(b[1]); v[6]=(short)f2bf(b[2]); v[7]=(short)f2bf(b[3]);
  return v;
}

// ---------------------------------------------------------------------------
// Kernel 1: Wo -> bf16
__global__ __launch_bounds__(256) void cast_wo_kernel(
    const float* __restrict__ Wo, unsigned short* __restrict__ Wob){
  int i = blockIdx.x * 256 + threadIdx.x;
  Wob[i] = f2bf(Wo[i]);
}

// ---------------------------------------------------------------------------
// Kernel 2: QKV projection. Q,K stored [n][h][p][hd] bf16; V stored transposed
// [n][h][hd][p] bf16 so PV B-fragments are contiguous.
__global__ __launch_bounds__(256) void qkv_kernel(
    const float* __restrict__ x, const float* __restrict__ Wq,
    const float* __restrict__ Wk, const float* __restrict__ Wv,
    unsigned short* __restrict__ Q, unsigned short* __restrict__ K,
    unsigned short* __restrict__ Vt)
{
  const int n = blockIdx.z, h = blockIdx.y, pt = blockIdx.x;
  const int tid = threadIdx.x;
  const int wave = tid >> 6, lane = tid & 63, quad = lane >> 4, ln = lane & 15;
  const int p0 = pt * 64 + wave * 16;

  // A-frag: x[n][p0+ln][h*64 + quad*8 + 32*half .. +8]  (m=ln, k=quad*8+j)
  const float* xp = x + ((size_t)(n * P_ + p0 + ln)) * D_ + h * HD_ + quad * 8;
  short8 af0 = load8f_bf(xp);
  short8 af1 = load8f_bf(xp + 32);

  const size_t slab = ((size_t)(n * H_ + h)) * (size_t)P_ * HD_;
  const float* Ws[3] = {Wq, Wk, Wv};
  #pragma unroll
  for (int mat = 0; mat < 3; mat++){
    const float* W = Ws[mat];
    #pragma unroll
    for (int et = 0; et < 4; et++){
      // B-frag: B[k=d][n=e] = W[e][d] -> row e=et*16+ln, 8 consecutive d
      const float* wp = W + (et * 16 + ln) * HD_ + quad * 8;
      short8 b0 = load8f_bf(wp);
      short8 b1 = load8f_bf(wp + 32);
      f32x4 c = {0.f, 0.f, 0.f, 0.f};
      c = mfma16(af0, b0, c);
      c = mfma16(af1, b1, c);
      // C layout: row(p) = quad*4+r, col(e) = et*16+ln
      #pragma unroll
      for (int r = 0; r < 4; r++){
        unsigned short v = f2bf(c[r]);
        int prow = p0 + quad * 4 + r;
        if (mat == 0)      Q [slab + (size_t)prow * HD_ + et * 16 + ln] = v;
        else if (mat == 1) K [slab + (size_t)prow * HD_ + et * 16 + ln] = v;
        else               Vt[slab + (size_t)(et * 16 + ln) * P_ + prow] = v;
      }
    }
  }
}

// ---------------------------------------------------------------------------
// Kernel 3: fused attention.
// Block = (n, h, 32 q-rows), 4 waves: wave = g*2+hf, g = 16-row group,
// hf = key-half [hf*1024, hf*1024+1024). Doubles grid to 2048 blocks ->
// 32 waves/CU (was 16: latency-bound at Occupancy 40%, MfmaUtil 5%).
// Pass A: partial l over own key-half (register-double-buffered K loads),
// combined across the wave pair via LDS.
// Pass B: recompute S over own half, P = exp*rinv, transpose via per-wave
// LDS tile, nontemporal fp32 attention store (512 MB stream, never re-read),
// partial P*V accumulate; o combined across wave pair via LDS.
__global__ __launch_bounds__(256, 8) void attn_kernel(
    const unsigned short* __restrict__ Q, const unsigned short* __restrict__ K,
    const unsigned short* __restrict__ Vt, float* __restrict__ attn,
    unsigned short* __restrict__ O1)
{
  __shared__ __align__(16) unsigned short ptile[4][16 * 40]; // 40-stride kills b128 conflicts
  __shared__ float lsum[4][4][4];        // [wave][quad][r]
  __shared__ float osum[2][64][17];      // [g][lane][dt*4+r], pad 17 vs 32-bank stride
  const int n = blockIdx.z, h = blockIdx.y, qt = blockIdx.x;
  const int tid = threadIdx.x;
  const int wave = tid >> 6, lane = tid & 63, quad = lane >> 4, ln = lane & 15;
  const int g = wave >> 1, hf = wave & 1;
  const int q0 = qt * 32 + g * 16;
  const float scale = 0.04419417382415922f; // 1/sqrt(512)

  const size_t slab = ((size_t)(n * H_ + h)) * (size_t)P_ * HD_;
  const unsigned short* Qs = Q + slab;
  const unsigned short* Ks = K + slab;
  const unsigned short* Vs = Vt + slab;

  short8 qf0 = *(const short8*)(Qs + (size_t)(q0 + ln) * HD_ + quad * 8);
  short8 qf1 = *(const short8*)(Qs + (size_t)(q0 + ln) * HD_ + quad * 8 + 32);

  // ---- Pass A: partial row sums of exp over this wave's key-half ----
  const unsigned short* kp0 = Ks + (size_t)(hf * (P_ / 2) + ln) * HD_ + quad * 8;
  short8 kf0 = *(const short8*)kp0;
  short8 kf1 = *(const short8*)(kp0 + 32);
  f32x4 l = {0.f, 0.f, 0.f, 0.f};
  for (int kt = 0; kt < P_ / 32; kt++){   // 64 iters x 16 keys
    short8 c0 = kf0, c1 = kf1;
    if (kt < P_ / 32 - 1){
      const unsigned short* np = kp0 + (size_t)(kt + 1) * 16 * HD_;
      kf0 = *(const short8*)np;
      kf1 = *(const short8*)(np + 32);
    }
    f32x4 s = {0.f, 0.f, 0.f, 0.f};
    s = mfma16(qf0, c0, s);
    s = mfma16(qf1, c1, s);
    #pragma unroll
    for (int r = 0; r < 4; r++) l[r] += __expf(s[r] * scale);
  }
  #pragma unroll
  for (int m = 1; m < 16; m <<= 1){
    #pragma unroll
    for (int r = 0; r < 4; r++) l[r] += __shfl_xor(l[r], m, 64);
  }
  if (ln == 0){
    #pragma unroll
    for (int r = 0; r < 4; r++) lsum[wave][quad][r] = l[r];
  }
  __syncthreads();
  f32x4 rinv;
  #pragma unroll
  for (int r = 0; r < 4; r++) rinv[r] = 1.0f / (l[r] + lsum[wave ^ 1][quad][r]);

  // ---- Pass B over this wave's key-half ----
  f32x4 o[4] = {{0,0,0,0},{0,0,0,0},{0,0,0,0},{0,0,0,0}};
  unsigned short* pl = ptile[wave];
  float* arow = attn + ((size_t)((n * H_ + h) * P_ + q0 + ln)) * P_;
  const int kgbeg = hf * (P_ / 64);     // 32 kg-units of 32 keys each
  for (int i = 0; i < P_ / 64; i++){
    int kg = kgbeg + i;
    #pragma unroll
    for (int t = 0; t < 2; t++){
      int kt = kg * 2 + t;
      const unsigned short* kp = Ks + (size_t)(kt * 16 + ln) * HD_ + quad * 8;
      short8 ka = *(const short8*)kp;
      short8 kb = *(const short8*)(kp + 32);
      f32x4 s = {0.f, 0.f, 0.f, 0.f};
      s = mfma16(qf0, ka, s);
      s = mfma16(qf1, kb, s);
      #pragma unroll
      for (int r = 0; r < 4; r++){
        float p = __expf(s[r] * scale) * rinv[r];
        // C layout: row q = quad*4+r, col k = t*16+ln
        pl[(quad * 4 + r) * 40 + t * 16 + ln] = f2bf(p);
      }
    }
    asm volatile("s_waitcnt lgkmcnt(0)" ::: "memory");
    // A-layout read: P[q=ln][k = kg*32 + quad*8 + j]
    short8 pf = *(const short8*)(pl + ln * 40 + quad * 8);
    // attention store: 8 consecutive keys for row q0+ln, fp32, nontemporal
    f32x4 pa, pb;
    #pragma unroll
    for (int j = 0; j < 4; j++) pa[j] = bf2f((unsigned short)pf[j]);
    #pragma unroll
    for (int j = 0; j < 4; j++) pb[j] = bf2f((unsigned short)pf[4 + j]);
    float* ap = arow + kg * 32 + quad * 8;
    __builtin_nontemporal_store(pa, (f32x4*)ap);
    __builtin_nontemporal_store(pb, (f32x4*)(ap + 4));
    // P*V: B-frag = Vt[d = dt*16+ln][key = kg*32 + quad*8 + j]
    #pragma unroll
    for (int dt = 0; dt < 4; dt++){
      short8 vf = *(const short8*)(Vs + (size_t)(dt * 16 + ln) * P_ + kg * 32 + quad * 8);
      o[dt] = mfma16(pf, vf, o[dt]);
    }
  }

  // ---- combine partial o across the wave pair, epilogue by hf==0 waves ----
  if (hf){
    #pragma unroll
    for (int dt = 0; dt < 4; dt++){
      #pragma unroll
      for (int r = 0; r < 4; r++) osum[g][lane][dt * 4 + r] = o[dt][r];
    }
  }
  __syncthreads();
  if (!hf){
    #pragma unroll
    for (int dt = 0; dt < 4; dt++){
      #pragma unroll
      for (int r = 0; r < 4; r++){
        float val = o[dt][r] + osum[g][lane][dt * 4 + r];
        int prow = q0 + quad * 4 + r;
        O1[((size_t)(n * P_ + prow)) * D_ + h * HD_ + dt * 16 + ln] = f2bf(val);
      }
    }
  }
}

// ---------------------------------------------------------------------------
// Kernel 4: out = O1 @ Wo^T + bo  (M=8192, N=512, K=512, bf16 MFMA, fp32 out)
__global__ __launch_bounds__(256) void oproj_kernel(
    const unsigned short* __restrict__ O1, const unsigned short* __restrict__ Wob,
    const float* __restrict__ bo, float* __restrict__ out)
{
  const int mb = blockIdx.x, nb = blockIdx.y;
  const int tid = threadIdx.x;
  const int wave = tid >> 6, lane = tid & 63, quad = lane >> 4, ln = lane & 15;
  const int row0 = mb * 64 + wave * 16;
  const int col0 = nb * 64;
  f32x4 acc[4] = {{0,0,0,0},{0,0,0,0},{0,0,0,0},{0,0,0,0}};
  for (int ks = 0; ks < D_ / 32; ks++){
    short8 af = *(const short8*)(O1 + (size_t)(row0 + ln) * D_ + ks * 32 + quad * 8);
    #pragma unroll
    for (int et = 0; et < 4; et++){
      short8 bf = *(const short8*)(Wob + (size_t)(col0 + et * 16 + ln) * D_ + ks * 32 + quad * 8);
      acc[et] = mfma16(af, bf, acc[et]);
    }
  }
  #pragma unroll
  for (int et = 0; et < 4; et++){
    float b = bo[col0 + et * 16 + ln];
    #pragma unroll
    for (int r = 0; r < 4; r++){
      out[(size_t)(row0 + quad * 4 + r) * D_ + col0 + et * 16 + ln] = acc[et][r] + b;
    }
  }
}

// ---------------------------------------------------------------------------
extern "C" void kernel_launch(void* const* d_in, const int* in_sizes, int n_in,
                              void* d_out, int out_size, void* d_ws, size_t ws_size,
                              hipStream_t stream)
{
  (void)in_sizes; (void)n_in; (void)out_size; (void)ws_size;
  const float* xyz = (const float*)d_in[0];
  const float* Wq  = (const float*)d_in[1];
  const float* Wk  = (const float*)d_in[2];
  const float* Wv  = (const float*)d_in[3];
  const float* Wo  = (const float*)d_in[4];
  const float* bo  = (const float*)d_in[5];

  float* out  = (float*)d_out;                                  // (N,P,D)
  float* attn = out + (size_t)N_ * P_ * D_;                     // (N,H,P,P)

  unsigned char* ws = (unsigned char*)d_ws;
  unsigned short* Q   = (unsigned short*)(ws);                          // 8 MiB
  unsigned short* K   = (unsigned short*)(ws + (size_t)8  * 1024 * 1024);
  unsigned short* Vt  = (unsigned short*)(ws + (size_t)16 * 1024 * 1024);
  unsigned short* O1  = (unsigned short*)(ws + (size_t)24 * 1024 * 1024);
  unsigned short* Wob = (unsigned short*)(ws + (size_t)32 * 1024 * 1024); // 512 KiB

  hipLaunchKernelGGL(cast_wo_kernel, dim3((D_ * D_) / 256), dim3(256), 0, stream, Wo, Wob);
  hipLaunchKernelGGL(qkv_kernel, dim3(P_ / 64, H_, N_), dim3(256), 0, stream,
                     xyz, Wq, Wk, Wv, Q, K, Vt);
  hipLaunchKernelGGL(attn_kernel, dim3(P_ / 32, H_, N_), dim3(256), 0, stream,
                     Q, K, Vt, attn, O1);
  hipLaunchKernelGGL(oproj_kernel, dim3((N_ * P_) / 64, D_ / 64, 1), dim3(256), 0, stream,
                     O1, Wob, bo, out);
}

// Round 2
// 876.994 us; speedup vs baseline: 1.0530x; 1.0148x over previous
//
#include <hip/hip_runtime.h>

#define N_ 4
#define P_ 2048
#define D_ 512
#define H_ 8
#define HD_ 64

typedef __attribute__((ext_vector_type(8))) short short8;
typedef __attribute__((ext_vector_type(4))) short shortv4;
typedef __attribute__((ext_vector_type(4))) float f32x4;

__device__ __forceinline__ f32x4 mfma16(short8 a, short8 b, f32x4 c){
  return __builtin_amdgcn_mfma_f32_16x16x32_bf16(a, b, c, 0, 0, 0);
}

__device__ __forceinline__ unsigned short f2bf(float f){
  union { float fv; unsigned u; } v; v.fv = f;
  unsigned r = v.u + 0x7fffu + ((v.u >> 16) & 1u);
  return (unsigned short)(r >> 16);
}
__device__ __forceinline__ float bf2f(unsigned short b){
  union { unsigned u; float fv; } v; v.u = ((unsigned)b) << 16;
  return v.fv;
}
__device__ __forceinline__ short8 load8f_bf(const float* p){
  f32x4 a = *(const f32x4*)p;
  f32x4 b = *(const f32x4*)(p + 4);
  short8 v;
  v[0]=(short)f2bf(a[0]); v[1]=(short)f2bf(a[1]); v[2]=(short)f2bf(a[2]); v[3]=(short)f2bf(a[3]);
  v[4]=(short)f2bf(b[0]); v[5]=(short)f2bf(b[1]); v[6]=(short)f2bf(b[2]); v[7]=(short)f2bf(b[3]);
  return v;
}

// ---------------------------------------------------------------------------
// Kernel 1: Wo -> bf16
__global__ __launch_bounds__(256) void cast_wo_kernel(
    const float* __restrict__ Wo, unsigned short* __restrict__ Wob){
  int i = blockIdx.x * 256 + threadIdx.x;
  Wob[i] = f2bf(Wo[i]);
}

// ---------------------------------------------------------------------------
// Kernel 2: QKV projection. Q,K stored [n][h][p][hd] bf16; V stored transposed
// [n][h][hd][p] bf16 so PV B-fragments are contiguous.
__global__ __launch_bounds__(256) void qkv_kernel(
    const float* __restrict__ x, const float* __restrict__ Wq,
    const float* __restrict__ Wk, const float* __restrict__ Wv,
    unsigned short* __restrict__ Q, unsigned short* __restrict__ K,
    unsigned short* __restrict__ Vt)
{
  const int n = blockIdx.z, h = blockIdx.y, pt = blockIdx.x;
  const int tid = threadIdx.x;
  const int wave = tid >> 6, lane = tid & 63, quad = lane >> 4, ln = lane & 15;
  const int p0 = pt * 64 + wave * 16;

  // A-frag: x[n][p0+ln][h*64 + quad*8 + 32*half .. +8]  (m=ln, k=quad*8+j)
  const float* xp = x + ((size_t)(n * P_ + p0 + ln)) * D_ + h * HD_ + quad * 8;
  short8 af0 = load8f_bf(xp);
  short8 af1 = load8f_bf(xp + 32);

  const size_t slab = ((size_t)(n * H_ + h)) * (size_t)P_ * HD_;
  const float* Ws[3] = {Wq, Wk, Wv};
  #pragma unroll
  for (int mat = 0; mat < 3; mat++){
    const float* W = Ws[mat];
    #pragma unroll
    for (int et = 0; et < 4; et++){
      // B-frag: B[k=d][n=e] = W[e][d] -> row e=et*16+ln, 8 consecutive d
      const float* wp = W + (et * 16 + ln) * HD_ + quad * 8;
      short8 b0 = load8f_bf(wp);
      short8 b1 = load8f_bf(wp + 32);
      f32x4 c = {0.f, 0.f, 0.f, 0.f};
      c = mfma16(af0, b0, c);
      c = mfma16(af1, b1, c);
      // C layout: row(p) = quad*4+r, col(e) = et*16+ln
      #pragma unroll
      for (int r = 0; r < 4; r++){
        unsigned short v = f2bf(c[r]);
        int prow = p0 + quad * 4 + r;
        if (mat == 0)      Q [slab + (size_t)prow * HD_ + et * 16 + ln] = v;
        else if (mat == 1) K [slab + (size_t)prow * HD_ + et * 16 + ln] = v;
        else               Vt[slab + (size_t)(et * 16 + ln) * P_ + prow] = v;
      }
    }
  }
}

// ---------------------------------------------------------------------------
// Kernel 3: fused attention.
// Block = (n, h, 32 q-rows), 4 waves: wave = g*2+hf, g = 16-row group,
// hf = key-half [hf*1024, hf*1024+1024).
// Pass A: partial l over own key-half (register-double-buffered K loads),
// combined across the wave pair via LDS.
// Pass B: recompute S over own half, P = exp*rinv, transpose via per-wave
// LDS tile. Attention store: FULL-SECTOR nontemporal stores — each store
// instruction covers bytes [0,64) or [64,128) of a 128B row-chunk completely
// (quads write 4x16B contiguous), so NT never emits masked partial-sector
// writes (round-1 WRITE_SIZE showed 27% HBM write amplification = ECC RMW
// from interleaved pa/pb half-lines). MFMA A-frag still read at quad*8.
__global__ __launch_bounds__(256, 8) void attn_kernel(
    const unsigned short* __restrict__ Q, const unsigned short* __restrict__ K,
    const unsigned short* __restrict__ Vt, float* __restrict__ attn,
    unsigned short* __restrict__ O1)
{
  __shared__ __align__(16) unsigned short ptile[4][16 * 40]; // 40-stride kills b128 conflicts
  __shared__ float lsum[4][4][4];        // [wave][quad][r]
  __shared__ float osum[2][64][17];      // [g][lane][dt*4+r], pad 17 vs 32-bank stride
  const int n = blockIdx.z, h = blockIdx.y, qt = blockIdx.x;
  const int tid = threadIdx.x;
  const int wave = tid >> 6, lane = tid & 63, quad = lane >> 4, ln = lane & 15;
  const int g = wave >> 1, hf = wave & 1;
  const int q0 = qt * 32 + g * 16;
  const float scale = 0.04419417382415922f; // 1/sqrt(512)

  const size_t slab = ((size_t)(n * H_ + h)) * (size_t)P_ * HD_;
  const unsigned short* Qs = Q + slab;
  const unsigned short* Ks = K + slab;
  const unsigned short* Vs = Vt + slab;

  short8 qf0 = *(const short8*)(Qs + (size_t)(q0 + ln) * HD_ + quad * 8);
  short8 qf1 = *(const short8*)(Qs + (size_t)(q0 + ln) * HD_ + quad * 8 + 32);

  // ---- Pass A: partial row sums of exp over this wave's key-half ----
  const unsigned short* kp0 = Ks + (size_t)(hf * (P_ / 2) + ln) * HD_ + quad * 8;
  short8 kf0 = *(const short8*)kp0;
  short8 kf1 = *(const short8*)(kp0 + 32);
  f32x4 l = {0.f, 0.f, 0.f, 0.f};
  for (int kt = 0; kt < P_ / 32; kt++){   // 64 iters x 16 keys
    short8 c0 = kf0, c1 = kf1;
    if (kt < P_ / 32 - 1){
      const unsigned short* np = kp0 + (size_t)(kt + 1) * 16 * HD_;
      kf0 = *(const short8*)np;
      kf1 = *(const short8*)(np + 32);
    }
    f32x4 s = {0.f, 0.f, 0.f, 0.f};
    s = mfma16(qf0, c0, s);
    s = mfma16(qf1, c1, s);
    #pragma unroll
    for (int r = 0; r < 4; r++) l[r] += __expf(s[r] * scale);
  }
  #pragma unroll
  for (int m = 1; m < 16; m <<= 1){
    #pragma unroll
    for (int r = 0; r < 4; r++) l[r] += __shfl_xor(l[r], m, 64);
  }
  if (ln == 0){
    #pragma unroll
    for (int r = 0; r < 4; r++) lsum[wave][quad][r] = l[r];
  }
  __syncthreads();
  f32x4 rinv;
  #pragma unroll
  for (int r = 0; r < 4; r++) rinv[r] = 1.0f / (l[r] + lsum[wave ^ 1][quad][r]);

  // ---- Pass B over this wave's key-half ----
  f32x4 o[4] = {{0,0,0,0},{0,0,0,0},{0,0,0,0},{0,0,0,0}};
  unsigned short* pl = ptile[wave];
  float* arow = attn + ((size_t)((n * H_ + h) * P_ + q0 + ln)) * P_;
  const int kgbeg = hf * (P_ / 64);     // 32 kg-units of 32 keys each
  for (int i = 0; i < P_ / 64; i++){
    int kg = kgbeg + i;
    #pragma unroll
    for (int t = 0; t < 2; t++){
      int kt = kg * 2 + t;
      const unsigned short* kp = Ks + (size_t)(kt * 16 + ln) * HD_ + quad * 8;
      short8 ka = *(const short8*)kp;
      short8 kb = *(const short8*)(kp + 32);
      f32x4 s = {0.f, 0.f, 0.f, 0.f};
      s = mfma16(qf0, ka, s);
      s = mfma16(qf1, kb, s);
      #pragma unroll
      for (int r = 0; r < 4; r++){
        float p = __expf(s[r] * scale) * rinv[r];
        // C layout: row q = quad*4+r, col k = t*16+ln
        pl[(quad * 4 + r) * 40 + t * 16 + ln] = f2bf(p);
      }
    }
    asm volatile("s_waitcnt lgkmcnt(0)" ::: "memory");
    // A-layout read for PV MFMA: P[q=ln][k = kg*32 + quad*8 + j]
    short8 pf = *(const short8*)(pl + ln * 40 + quad * 8);
    // Store-gather reads: lane gets 4 CONSECUTIVE keys at quad*4 so each
    // store instruction covers a full 64B sector of the row.
    shortv4 qa = *(const shortv4*)(pl + ln * 40 + quad * 4);
    shortv4 qb = *(const shortv4*)(pl + ln * 40 + 16 + quad * 4);
    f32x4 pa, pb;
    #pragma unroll
    for (int j = 0; j < 4; j++) pa[j] = bf2f((unsigned short)qa[j]);
    #pragma unroll
    for (int j = 0; j < 4; j++) pb[j] = bf2f((unsigned short)qb[j]);
    float* ap = arow + kg * 32;
    __builtin_nontemporal_store(pa, (f32x4*)(ap + quad * 4));
    __builtin_nontemporal_store(pb, (f32x4*)(ap + 16 + quad * 4));
    // P*V: B-frag = Vt[d = dt*16+ln][key = kg*32 + quad*8 + j]
    #pragma unroll
    for (int dt = 0; dt < 4; dt++){
      short8 vf = *(const short8*)(Vs + (size_t)(dt * 16 + ln) * P_ + kg * 32 + quad * 8);
      o[dt] = mfma16(pf, vf, o[dt]);
    }
  }

  // ---- combine partial o across the wave pair, epilogue by hf==0 waves ----
  if (hf){
    #pragma unroll
    for (int dt = 0; dt < 4; dt++){
      #pragma unroll
      for (int r = 0; r < 4; r++) osum[g][lane][dt * 4 + r] = o[dt][r];
    }
  }
  __syncthreads();
  if (!hf){
    #pragma unroll
    for (int dt = 0; dt < 4; dt++){
      #pragma unroll
      for (int r = 0; r < 4; r++){
        float val = o[dt][r] + osum[g][lane][dt * 4 + r];
        int prow = q0 + quad * 4 + r;
        O1[((size_t)(n * P_ + prow)) * D_ + h * HD_ + dt * 16 + ln] = f2bf(val);
      }
    }
  }
}

// ---------------------------------------------------------------------------
// Kernel 4: out = O1 @ Wo^T + bo  (M=8192, N=512, K=512, bf16 MFMA, fp32 out)
__global__ __launch_bounds__(256) void oproj_kernel(
    const unsigned short* __restrict__ O1, const unsigned short* __restrict__ Wob,
    const float* __restrict__ bo, float* __restrict__ out)
{
  const int mb = blockIdx.x, nb = blockIdx.y;
  const int tid = threadIdx.x;
  const int wave = tid >> 6, lane = tid & 63, quad = lane >> 4, ln = lane & 15;
  const int row0 = mb * 64 + wave * 16;
  const int col0 = nb * 64;
  f32x4 acc[4] = {{0,0,0,0},{0,0,0,0},{0,0,0,0},{0,0,0,0}};
  for (int ks = 0; ks < D_ / 32; ks++){
    short8 af = *(const short8*)(O1 + (size_t)(row0 + ln) * D_ + ks * 32 + quad * 8);
    #pragma unroll
    for (int et = 0; et < 4; et++){
      short8 bf = *(const short8*)(Wob + (size_t)(col0 + et * 16 + ln) * D_ + ks * 32 + quad * 8);
      acc[et] = mfma16(af, bf, acc[et]);
    }
  }
  #pragma unroll
  for (int et = 0; et < 4; et++){
    float b = bo[col0 + et * 16 + ln];
    #pragma unroll
    for (int r = 0; r < 4; r++){
      out[(size_t)(row0 + quad * 4 + r) * D_ + col0 + et * 16 + ln] = acc[et][r] + b;
    }
  }
}

// ---------------------------------------------------------------------------
extern "C" void kernel_launch(void* const* d_in, const int* in_sizes, int n_in,
                              void* d_out, int out_size, void* d_ws, size_t ws_size,
                              hipStream_t stream)
{
  (void)in_sizes; (void)n_in; (void)out_size; (void)ws_size;
  const float* xyz = (const float*)d_in[0];
  const float* Wq  = (const float*)d_in[1];
  const float* Wk  = (const float*)d_in[2];
  const float* Wv  = (const float*)d_in[3];
  const float* Wo  = (const float*)d_in[4];
  const float* bo  = (const float*)d_in[5];

  float* out  = (float*)d_out;                                  // (N,P,D)
  float* attn = out + (size_t)N_ * P_ * D_;                     // (N,H,P,P)

  unsigned char* ws = (unsigned char*)d_ws;
  unsigned short* Q   = (unsigned short*)(ws);                          // 8 MiB
  unsigned short* K   = (unsigned short*)(ws + (size_t)8  * 1024 * 1024);
  unsigned short* Vt  = (unsigned short*)(ws + (size_t)16 * 1024 * 1024);
  unsigned short* O1  = (unsigned short*)(ws + (size_t)24 * 1024 * 1024);
  unsigned short* Wob = (unsigned short*)(ws + (size_t)32 * 1024 * 1024); // 512 KiB

  hipLaunchKernelGGL(cast_wo_kernel, dim3((D_ * D_) / 256), dim3(256), 0, stream, Wo, Wob);
  hipLaunchKernelGGL(qkv_kernel, dim3(P_ / 64, H_, N_), dim3(256), 0, stream,
                     xyz, Wq, Wk, Wv, Q, K, Vt);
  hipLaunchKernelGGL(attn_kernel, dim3(P_ / 32, H_, N_), dim3(256), 0, stream,
                     Q, K, Vt, attn, O1);
  hipLaunchKernelGGL(oproj_kernel, dim3((N_ * P_) / 64, D_ / 64, 1), dim3(256), 0, stream,
                     O1, Wob, bo, out);
}